// Round 1
// baseline (602.420 us; speedup 1.0000x reference)
//
#include <hip/hip_runtime.h>

// Input:  x (16,128,128,128) fp32  -> 2048 planes of 128x128
// Output: y (16,128,256,256) fp32
//
// Derived separable stencil (from reflect-pad(2) + upfirdn2d up=2, k=[1,4,6,4,1]^2/256, gain=4):
//   even out 2j   = 0.5   * (s[refl(j-1)] + s[j])
//   odd  out 2j+1 = 0.125 * (s[refl(j-1)] + 6*s[j] + s[refl(j+1)])
// applied along H then W. refl(-1)=1, refl(128)=126.

constexpr int H = 128, W = 128, OH = 256, OW = 256;
constexpr int YPT = 4;  // input rows (=> 2x2 output blocks) per thread

__global__ __launch_bounds__(256)
void up2x_kernel(const float* __restrict__ x, float* __restrict__ out) {
    const int jx = threadIdx.x;                                        // 0..127
    const int ybase = (blockIdx.y * blockDim.y + threadIdx.y) * YPT;   // 0,4,..,124
    const int plane = blockIdx.z;                                      // 0..planes-1

    const float* __restrict__ xin = x + (size_t)plane * (H * W);
    float* __restrict__ o = out + (size_t)plane * (OH * OW);

    const int xm  = (jx == 0)     ? 1     : jx - 1;   // refl(jx-1)
    const int xp1 = (jx == W - 1) ? W - 2 : jx + 1;   // refl(jx+1)

    // a = row refl(ybase-1), b = row ybase (3-col neighborhood each)
    const int ra = (ybase == 0) ? 1 : ybase - 1;
    const float* pa = xin + ra * W;
    const float* pb = xin + ybase * W;
    float a0 = pa[xm], a1 = pa[jx], a2 = pa[xp1];
    float b0 = pb[xm], b1 = pb[jx], b2 = pb[xp1];

    #pragma unroll
    for (int t = 0; t < YPT; ++t) {
        const int jy = ybase + t;
        const int rc = (jy == H - 1) ? H - 2 : jy + 1;   // refl(jy+1)
        const float* pc = xin + rc * W;
        const float c0 = pc[xm], c1 = pc[jx], c2 = pc[xp1];

        // vertical combine: e* feeds even output row 2jy, q* feeds odd row 2jy+1
        const float e0 = 0.5f * (a0 + b0);
        const float e1 = 0.5f * (a1 + b1);
        const float e2 = 0.5f * (a2 + b2);
        const float q0 = 0.125f * (a0 + 6.0f * b0 + c0);
        const float q1 = 0.125f * (a1 + 6.0f * b1 + c1);
        const float q2 = 0.125f * (a2 + 6.0f * b2 + c2);

        // horizontal combine -> 2x2 output block at (2jy, 2jx)
        float2 top, bot;
        top.x = 0.5f   * (e0 + e1);
        top.y = 0.125f * (e0 + 6.0f * e1 + e2);
        bot.x = 0.5f   * (q0 + q1);
        bot.y = 0.125f * (q0 + 6.0f * q1 + q2);

        const size_t obase = (size_t)(2 * jy) * OW + 2 * jx;
        *reinterpret_cast<float2*>(o + obase)      = top;
        *reinterpret_cast<float2*>(o + obase + OW) = bot;

        // slide window down one row
        a0 = b0; a1 = b1; a2 = b2;
        b0 = c0; b1 = c1; b2 = c2;
    }
}

extern "C" void kernel_launch(void* const* d_in, const int* in_sizes, int n_in,
                              void* d_out, int out_size, void* d_ws, size_t ws_size,
                              hipStream_t stream) {
    const float* x = (const float*)d_in[0];
    float* out = (float*)d_out;
    const int planes = in_sizes[0] / (H * W);  // 16*128 = 2048

    dim3 block(128, 2, 1);
    dim3 grid(1, H / (2 * YPT), planes);  // (1, 16, 2048)
    up2x_kernel<<<grid, block, 0, stream>>>(x, out);
}